// Round 1
// baseline (112.403 us; speedup 1.0000x reference)
//
#include <hip/hip_runtime.h>

#define NV 30000
#define NB 128
#define NS 512
#define ND 300
#define NC 300
#define CP 304     // padded C
#define KPAD 320   // padded K (=D) for GEMM
#define MASK_NEG -1e9f
#define SQ_EPS 1e-8f

typedef __attribute__((ext_vector_type(4))) float f32x4;
typedef __attribute__((ext_vector_type(8))) __bf16 bf16x8;

__device__ __forceinline__ unsigned short f2bf(float x){
  unsigned int u = __float_as_uint(x);
  u += 0x7FFFu + ((u >> 16) & 1u);
  return (unsigned short)(u >> 16);
}
__device__ __forceinline__ float bf2f(unsigned short h){
  return __uint_as_float(((unsigned int)h) << 16);
}

// ---------------- K0: prep (Wt bf16 transpose, W_att^T, gw^T, bspad, guide squash)
__global__ __launch_bounds__(320) void k0_prep(
    const float* __restrict__ Ws, const float* __restrict__ Watt,
    const float* __restrict__ Gw, const float* __restrict__ bs,
    const float* __restrict__ gcap,
    unsigned short* __restrict__ wt, float* __restrict__ att_t,
    float* __restrict__ gwt, float* __restrict__ bsp, float* __restrict__ gpad)
{
  int bid = blockIdx.x, tid = threadIdx.x;
  __shared__ float red[320];
  if (bid < 80) {                       // wt[n][k] = bf16(Ws[k][n]), 320x320 padded
    #pragma unroll
    for (int r = 0; r < 4; r++){
      int id = bid*1280 + r*320 + tid;  // < 102400
      int n = id / 320, k = id - n*320;
      float v = (n < NC && k < ND) ? Ws[k*NC + n] : 0.f;
      wt[n*KPAD + k] = f2bf(v);
    }
  } else if (bid < 151) {               // att_t[d][c] = Watt[c][d]
    #pragma unroll
    for (int r = 0; r < 4; r++){
      int id = (bid-80)*1280 + r*320 + tid;
      if (id < ND*NC){ int c = id / ND, d = id - c*ND; att_t[d*CP + c] = Watt[id]; }
    }
  } else if (bid < 222) {               // gwt[d][c] = Gw[c][d]
    #pragma unroll
    for (int r = 0; r < 4; r++){
      int id = (bid-151)*1280 + r*320 + tid;
      if (id < ND*NC){ int c = id / ND, d = id - c*ND; gwt[d*CP + c] = Gw[id]; }
    }
  } else if (bid == 222) {              // bspad
    if (tid < CP) bsp[tid] = (tid < NC) ? bs[tid] : 0.f;
  } else {                              // guide squash, k = bid-223
    int k = bid - 223;
    float g = (tid < NC) ? gcap[k*NC + tid] : 0.f;
    red[tid] = g*g; __syncthreads();
    if (tid < 64){
      float s = red[tid]+red[tid+64]+red[tid+128]+red[tid+192]+red[tid+256];
      #pragma unroll
      for (int off = 32; off > 0; off >>= 1) s += __shfl_xor(s, off);
      if (tid == 0) red[0] = s;
    }
    __syncthreads();
    float sq = red[0];
    float ss = (sq/(1.f+sq))/sqrtf(sq + SQ_EPS);
    if (tid < CP) gpad[k*CP + tid] = g*ss;
  }
}

// ---------------- K2: aspect capsules -> t[b], and G[k][c]
#define ANB 4
__global__ __launch_bounds__(320) void k2_aspect(
    const int* __restrict__ aspect, const float* __restrict__ embed,
    const float* __restrict__ Wa, const float* __restrict__ ba,
    const float* __restrict__ att_t, const float* __restrict__ gwt,
    const float* __restrict__ gpad,
    float* __restrict__ tbuf, float* __restrict__ gbuf)
{
  int bid = blockIdx.x, tid = threadIdx.x;
  __shared__ float red[320];
  if (bid < NB/ANB) {
    __shared__ float vec[ANB][CP];
    int b0 = bid*ANB;
    for (int i = tid; i < ANB*CP; i += 320){
      int bi = i / CP, c = i - bi*CP;
      int a = aspect[b0 + bi];
      vec[bi][c] = (c < ND) ? embed[(size_t)a*ND + c] : 0.f;
    }
    __syncthreads();
    float z[ANB] = {0.f,0.f,0.f,0.f};
    if (tid < NC){
      #pragma unroll
      for (int i = 0; i < ANB; i++) z[i] = ba[tid];
      for (int d = 0; d < ND; d++){
        float wv = Wa[d*NC + tid];
        #pragma unroll
        for (int i = 0; i < ANB; i++) z[i] += vec[i][d]*wv;
      }
    }
    float ssv[ANB];
    for (int i = 0; i < ANB; i++){
      red[tid] = (tid < NC) ? z[i]*z[i] : 0.f;
      __syncthreads();
      if (tid < 64){
        float s = red[tid]+red[tid+64]+red[tid+128]+red[tid+192]+red[tid+256];
        #pragma unroll
        for (int off = 32; off > 0; off >>= 1) s += __shfl_xor(s, off);
        if (tid == 0) red[0] = s;
      }
      __syncthreads();
      float sq = red[0];
      ssv[i] = (sq/(1.f+sq))/sqrtf(sq + SQ_EPS);
      __syncthreads();
    }
    if (tid < CP){
      #pragma unroll
      for (int i = 0; i < ANB; i++) vec[i][tid] = (tid < NC) ? z[i]*ssv[i] : 0.f;
    }
    __syncthreads();
    float t[ANB] = {0.f,0.f,0.f,0.f};
    if (tid < NC){
      for (int d = 0; d < ND; d++){
        float av = att_t[d*CP + tid];
        #pragma unroll
        for (int i = 0; i < ANB; i++) t[i] += av*vec[i][d];
      }
    }
    if (tid < CP){
      #pragma unroll
      for (int i = 0; i < ANB; i++) tbuf[(b0+i)*CP + tid] = (tid < NC) ? t[i] : 0.f;
    }
  } else {
    int k = bid - NB/ANB;   // 0..2
    float t = 0.f;
    if (tid < NC){
      for (int d = 0; d < ND; d++) t += gwt[d*CP + tid]*gpad[k*CP + d];
    }
    if (tid < CP) gbuf[k*CP + tid] = (tid < NC) ? t : 0.f;
  }
}

// ---------------- K1: E = embed @ W_s  (bf16 MFMA), E stored bf16 [30000][304]
#define BM 128
#define BKT 64
#define LDK 72
__global__ __launch_bounds__(512) void k1_gemm(
    const float* __restrict__ embed, const unsigned short* __restrict__ wt,
    unsigned short* __restrict__ E)
{
  __shared__ unsigned short lds_a[BM*LDK];
  __shared__ unsigned short lds_b[320*LDK];
  int tid = threadIdx.x;
  int lane = tid & 63, wid = tid >> 6;
  int wrow = wid >> 2, wcol = wid & 3;
  int rowbase = blockIdx.x * BM;
  f32x4 acc[4][5];
  f32x4 zero = {0.f,0.f,0.f,0.f};
  #pragma unroll
  for (int m = 0; m < 4; m++)
    #pragma unroll
    for (int n = 0; n < 5; n++) acc[m][n] = zero;

  for (int k0 = 0; k0 < KPAD; k0 += BKT){
    // stage A (f32 -> bf16)
    #pragma unroll
    for (int r = 0; r < 4; r++){
      int id = r*512 + tid;                 // < 2048
      int row = id >> 4, k4 = (id & 15) << 2;
      int gk = k0 + k4, grow = rowbase + row;
      float4 v = {0.f,0.f,0.f,0.f};
      if (grow < NV && gk < ND) v = *(const float4*)(embed + (size_t)grow*ND + gk);
      unsigned int lo = (unsigned int)f2bf(v.x) | ((unsigned int)f2bf(v.y) << 16);
      unsigned int hi = (unsigned int)f2bf(v.z) | ((unsigned int)f2bf(v.w) << 16);
      uint2 pk; pk.x = lo; pk.y = hi;
      *(uint2*)(lds_a + row*LDK + k4) = pk;
    }
    // stage B (already bf16, padded)
    #pragma unroll
    for (int r = 0; r < 5; r++){
      int id = r*512 + tid;                 // < 2560
      int n = id >> 3, koff = (id & 7) << 3;
      uint4 v = *(const uint4*)(wt + n*KPAD + k0 + koff);
      *(uint4*)(lds_b + n*LDK + koff) = v;
    }
    __syncthreads();
    #pragma unroll
    for (int kk = 0; kk < BKT; kk += 32){
      bf16x8 af[4], bfr[5];
      int kidx = kk + (lane >> 4)*8;
      int arow = wrow*64 + (lane & 15);
      int brow = wcol*80 + (lane & 15);
      #pragma unroll
      for (int m = 0; m < 4; m++) af[m] = *(const bf16x8*)(lds_a + (arow + m*16)*LDK + kidx);
      #pragma unroll
      for (int n = 0; n < 5; n++) bfr[n] = *(const bf16x8*)(lds_b + (brow + n*16)*LDK + kidx);
      #pragma unroll
      for (int m = 0; m < 4; m++)
        #pragma unroll
        for (int n = 0; n < 5; n++)
          acc[m][n] = __builtin_amdgcn_mfma_f32_16x16x32_bf16(af[m], bfr[n], acc[m][n], 0, 0, 0);
    }
    __syncthreads();
  }
  int colb = wcol*80 + (lane & 15);
  int rowb = rowbase + wrow*64 + ((lane >> 4) << 2);
  #pragma unroll
  for (int m = 0; m < 4; m++)
    #pragma unroll
    for (int n = 0; n < 5; n++)
      #pragma unroll
      for (int j = 0; j < 4; j++){
        int row = rowb + m*16 + j;
        int col = colb + n*16;
        if (row < NV && col < CP) E[(size_t)row*CP + col] = f2bf(acc[m][n][j]);
      }
}

// ---------------- K3: per-token score / u / ss (one wave per token)
__global__ __launch_bounds__(256) void k3_token(
    const int* __restrict__ sentence, const float* __restrict__ alphaA,
    const unsigned short* __restrict__ E, const float* __restrict__ tbuf,
    const float* __restrict__ gbuf, const float* __restrict__ bsp,
    float* __restrict__ scoreB, float* __restrict__ ssB, float* __restrict__ uuB)
{
  int tid = threadIdx.x;
  int lane = tid & 63;
  int wg = (blockIdx.x << 2) + (tid >> 6);
  int tok = sentence[wg];
  float al = alphaA[wg];
  int b = wg >> 9;
  const unsigned short* erow = E + (size_t)tok*CP;
  const float* trow = tbuf + b*CP;
  float sq = 0.f, sc = 0.f, u0 = 0.f, u1 = 0.f, u2 = 0.f;
  auto body = [&](int c){
    uint2 e2 = *(const uint2*)(erow + c);
    float4 tv = *(const float4*)(trow + c);
    float4 g0 = *(const float4*)(gbuf + c);
    float4 g1 = *(const float4*)(gbuf + CP + c);
    float4 g2 = *(const float4*)(gbuf + 2*CP + c);
    float4 bv = *(const float4*)(bsp + c);
    float y0 = al*bf2f((unsigned short)(e2.x & 0xffffu)) + bv.x;
    float y1 = al*bf2f((unsigned short)(e2.x >> 16)) + bv.y;
    float y2 = al*bf2f((unsigned short)(e2.y & 0xffffu)) + bv.z;
    float y3 = al*bf2f((unsigned short)(e2.y >> 16)) + bv.w;
    sq += y0*y0 + y1*y1 + y2*y2 + y3*y3;
    sc += y0*tv.x + y1*tv.y + y2*tv.z + y3*tv.w;
    u0 += y0*g0.x + y1*g0.y + y2*g0.z + y3*g0.w;
    u1 += y0*g1.x + y1*g1.y + y2*g1.z + y3*g1.w;
    u2 += y0*g2.x + y1*g2.y + y2*g2.z + y3*g2.w;
  };
  body(lane << 2);
  if (lane < 12) body(256 + (lane << 2));
  #pragma unroll
  for (int off = 32; off > 0; off >>= 1){
    sq += __shfl_xor(sq, off);
    sc += __shfl_xor(sc, off);
    u0 += __shfl_xor(u0, off);
    u1 += __shfl_xor(u1, off);
    u2 += __shfl_xor(u2, off);
  }
  if (lane == 0){
    float ssv = (sq/(1.f+sq))/sqrtf(sq + SQ_EPS);
    scoreB[wg] = (tok != 0) ? ssv*sc : MASK_NEG;
    ssB[wg] = ssv;
    uuB[wg*3+0] = ssv*u0;
    uuB[wg*3+1] = ssv*u1;
    uuB[wg*3+2] = ssv*u2;
  }
}

// ---------------- K4: per-b softmax over S, k-softmax, final weights
__global__ __launch_bounds__(512) void k4_softmax(
    const float* __restrict__ scoreB, const float* __restrict__ uuB,
    const float* __restrict__ ssB, const float* __restrict__ alphaA,
    const float* __restrict__ scale_p,
    float* __restrict__ coef, float* __restrict__ sb)
{
  int b = blockIdx.x, tid = threadIdx.x;
  int idx = (b << 9) + tid;
  __shared__ float red[512];
  float scv = scoreB[idx];
  red[tid] = scv; __syncthreads();
  if (tid < 64){
    float s = red[tid];
    #pragma unroll
    for (int o = 64; o < 512; o += 64) s = fmaxf(s, red[tid+o]);
    #pragma unroll
    for (int off = 32; off > 0; off >>= 1) s = fmaxf(s, __shfl_xor(s, off));
    if (tid == 0) red[0] = s;
  }
  __syncthreads();
  float m = red[0];
  __syncthreads();
  float e = expf(scv - m);
  red[tid] = e; __syncthreads();
  if (tid < 64){
    float s = 0.f;
    #pragma unroll
    for (int o = 0; o < 512; o += 64) s += red[tid+o];
    #pragma unroll
    for (int off = 32; off > 0; off >>= 1) s += __shfl_xor(s, off);
    if (tid == 0) red[0] = s;
  }
  __syncthreads();
  float Z = red[0];
  __syncthreads();
  float nw = e / Z;
  float v0 = uuB[idx*3+0], v1 = uuB[idx*3+1], v2 = uuB[idx*3+2];
  float mk = fmaxf(v0, fmaxf(v1, v2));
  float e0 = expf(v0-mk), e1 = expf(v1-mk), e2 = expf(v2-mk);
  float wf = nw * scale_p[0] / (e0+e1+e2);
  float w0 = e0*wf, w1 = e1*wf, w2 = e2*wf;
  float ssv = ssB[idx];
  float ca = ssv * alphaA[idx];
  coef[idx*3+0] = w0*ca; coef[idx*3+1] = w1*ca; coef[idx*3+2] = w2*ca;
  float s0 = w0*ssv, s1 = w1*ssv, s2 = w2*ssv;
  red[tid] = s0; __syncthreads();
  if (tid < 64){
    float s = 0.f;
    #pragma unroll
    for (int o = 0; o < 512; o += 64) s += red[tid+o];
    #pragma unroll
    for (int off = 32; off > 0; off >>= 1) s += __shfl_xor(s, off);
    if (tid == 0) sb[b*3+0] = s;
  }
  __syncthreads();
  red[tid] = s1; __syncthreads();
  if (tid < 64){
    float s = 0.f;
    #pragma unroll
    for (int o = 0; o < 512; o += 64) s += red[tid+o];
    #pragma unroll
    for (int off = 32; off > 0; off >>= 1) s += __shfl_xor(s, off);
    if (tid == 0) sb[b*3+1] = s;
  }
  __syncthreads();
  red[tid] = s2; __syncthreads();
  if (tid < 64){
    float s = 0.f;
    #pragma unroll
    for (int o = 0; o < 512; o += 64) s += red[tid+o];
    #pragma unroll
    for (int off = 32; off > 0; off >>= 1) s += __shfl_xor(s, off);
    if (tid == 0) sb[b*3+2] = s;
  }
}

// ---------------- K5: weighted gather-sum of E rows -> partial capsules
__global__ __launch_bounds__(320) void k5_accum(
    const int* __restrict__ sentence, const unsigned short* __restrict__ E,
    const float* __restrict__ coef, float* __restrict__ part)
{
  int bid = blockIdx.x;       // b*4 + ch ; token base = bid*128
  int tid = threadIdx.x;
  int tbase = bid << 7;
  __shared__ int toks[128];
  __shared__ float cfs[384];
  if (tid < 128) toks[tid] = sentence[tbase + tid];
  cfs[tid] = coef[tbase*3 + tid];
  if (tid < 64) cfs[320+tid] = coef[tbase*3 + 320 + tid];
  __syncthreads();
  if (tid < CP){
    float a0 = 0.f, a1 = 0.f, a2 = 0.f;
    for (int i = 0; i < 128; i++){
      float ev = bf2f(E[(size_t)toks[i]*CP + tid]);
      a0 += cfs[i*3+0]*ev;
      a1 += cfs[i*3+1]*ev;
      a2 += cfs[i*3+2]*ev;
    }
    float* p = part + (size_t)bid*3*CP;
    p[tid] = a0; p[CP+tid] = a1; p[2*CP+tid] = a2;
  }
}

// ---------------- K6: combine partials + bias term, squash-norm -> out
__global__ __launch_bounds__(320) void k6_norm(
    const float* __restrict__ part, const float* __restrict__ sb,
    const float* __restrict__ bsp, float* __restrict__ out)
{
  int bid = blockIdx.x;       // b*3 + k
  int b = bid / 3, k = bid - b*3;
  int tid = threadIdx.x;
  __shared__ float red[320];
  float v = 0.f;
  if (tid < CP){
    v = sb[bid]*bsp[tid];
    #pragma unroll
    for (int ch = 0; ch < 4; ch++)
      v += part[((size_t)(b*4+ch)*3 + k)*CP + tid];
  }
  red[tid] = v*v; __syncthreads();
  if (tid < 64){
    float s = red[tid]+red[tid+64]+red[tid+128]+red[tid+192]+red[tid+256];
    #pragma unroll
    for (int off = 32; off > 0; off >>= 1) s += __shfl_xor(s, off);
    if (tid == 0){
      float sq = s;
      out[bid] = (sq/(1.f+sq))*sqrtf(sq)/sqrtf(sq + SQ_EPS);
    }
  }
}

extern "C" void kernel_launch(void* const* d_in, const int* in_sizes, int n_in,
                              void* d_out, int out_size, void* d_ws, size_t ws_size,
                              hipStream_t stream)
{
  (void)in_sizes; (void)n_in; (void)out_size; (void)ws_size;
  const int*   sentence = (const int*)d_in[0];
  const int*   aspect   = (const int*)d_in[1];
  const float* alpha    = (const float*)d_in[2];
  const float* embed    = (const float*)d_in[3];
  const float* Ws       = (const float*)d_in[4];
  const float* bs       = (const float*)d_in[5];
  const float* Wa       = (const float*)d_in[6];
  const float* ba       = (const float*)d_in[7];
  const float* Watt     = (const float*)d_in[8];
  const float* gcap     = (const float*)d_in[9];
  const float* gw       = (const float*)d_in[10];
  const float* scale    = (const float*)d_in[11];
  float* out = (float*)d_out;

  char* w = (char*)d_ws;
  auto alloc = [&](size_t bytes)->char*{
    char* p = w; w += (bytes + 255) & ~(size_t)255; return p;
  };
  unsigned short* WT  = (unsigned short*)alloc((size_t)KPAD*KPAD*2);
  unsigned short* E   = (unsigned short*)alloc((size_t)NV*CP*2);
  float* ATT = (float*)alloc((size_t)ND*CP*4);
  float* GWT = (float*)alloc((size_t)ND*CP*4);
  float* BSP = (float*)alloc(CP*4);
  float* GPD = (float*)alloc(3*CP*4);
  float* TBF = (float*)alloc((size_t)NB*CP*4);
  float* GBF = (float*)alloc(3*CP*4);
  float* SCO = (float*)alloc((size_t)NB*NS*4);
  float* SSB = (float*)alloc((size_t)NB*NS*4);
  float* UUB = (float*)alloc((size_t)NB*NS*3*4);
  float* COF = (float*)alloc((size_t)NB*NS*3*4);
  float* SBB = (float*)alloc(NB*3*4);
  float* PRT = (float*)alloc((size_t)NB*4*3*CP*4);

  k0_prep<<<226, 320, 0, stream>>>(Ws, Watt, gw, bs, gcap, WT, ATT, GWT, BSP, GPD);
  k2_aspect<<<NB/ANB + 3, 320, 0, stream>>>(aspect, embed, Wa, ba, ATT, GWT, GPD, TBF, GBF);
  k1_gemm<<<(NV + BM - 1)/BM, 512, 0, stream>>>(embed, WT, E);
  k3_token<<<NB*NS/4, 256, 0, stream>>>(sentence, alpha, E, TBF, GBF, BSP, SCO, SSB, UUB);
  k4_softmax<<<NB, 512, 0, stream>>>(SCO, UUB, SSB, alpha, scale, COF, SBB);
  k5_accum<<<NB*4, 320, 0, stream>>>(sentence, E, COF, PRT);
  k6_norm<<<NB*3, 320, 0, stream>>>(PRT, SBB, BSP, out);
}